// Round 2
// baseline (651.644 us; speedup 1.0000x reference)
//
#include <hip/hip_runtime.h>
#include <math.h>

#define BATCHN 8
#define SEQN 4096
#define DMODEL 1024
#define MTOT (BATCHN*SEQN)      // 32768
#define VB_STRIDE 136           // 120 skew params | 16 Bx
#define CHUNKS 64               // chunks per batch
#define CLEN 64                 // SEQN / CHUNKS
#define YSIZE ((size_t)MTOT*DMODEL)

// ---------------- threefry2x32, jax_threefry_partitionable=True convention ----------------
// element I: counter pair (hi32(I)=0, lo32(I)=I); 32-bit output = out0 ^ out1.
__device__ __forceinline__ unsigned rotl32(unsigned x, int d){ return (x<<d)|(x>>(32-d)); }
__device__ __forceinline__ void tfr(unsigned &x0, unsigned &x1, int r){ x0 += x1; x1 = rotl32(x1,r); x1 ^= x0; }

// XLA ErfInv32 (Giles polynomial), w = -log1p(-x*x)
__device__ __forceinline__ float xla_erfinv(float x){
  float w = -log1pf(-x*x);
  float p;
  if (w < 5.0f){
    w = w - 2.5f;
    p = 2.81022636e-08f;
    p = fmaf(p, w, 3.43273939e-07f);
    p = fmaf(p, w, -3.5233877e-06f);
    p = fmaf(p, w, -4.39150654e-06f);
    p = fmaf(p, w, 0.00021858087f);
    p = fmaf(p, w, -0.00125372503f);
    p = fmaf(p, w, -0.00417768164f);
    p = fmaf(p, w, 0.246640727f);
    p = fmaf(p, w, 1.50140941f);
  } else {
    w = sqrtf(w) - 3.0f;
    p = -0.000200214257f;
    p = fmaf(p, w, 0.000100950558f);
    p = fmaf(p, w, 0.00134934322f);
    p = fmaf(p, w, -0.00367342844f);
    p = fmaf(p, w, 0.00573950773f);
    p = fmaf(p, w, -0.0076224613f);
    p = fmaf(p, w, 0.00943887047f);
    p = fmaf(p, w, 1.00167406f);
    p = fmaf(p, w, 2.83297682f);
  }
  return p * x;
}

__device__ float jax_randn(unsigned I){
  unsigned x0 = 0u;                // hi32 of element index (size < 2^32)
  unsigned x1 = I;                 // lo32
  const unsigned ks0 = 0u, ks1 = 1u, ks2 = 0x1BD11BDBu;  // 0^1^0x1BD11BDA
  x0 += ks0; x1 += ks1;
  tfr(x0,x1,13); tfr(x0,x1,15); tfr(x0,x1,26); tfr(x0,x1,6);
  x0 += ks1; x1 += ks2 + 1u;
  tfr(x0,x1,17); tfr(x0,x1,29); tfr(x0,x1,16); tfr(x0,x1,24);
  x0 += ks2; x1 += ks0 + 2u;
  tfr(x0,x1,13); tfr(x0,x1,15); tfr(x0,x1,26); tfr(x0,x1,6);
  x0 += ks0; x1 += ks1 + 3u;
  tfr(x0,x1,17); tfr(x0,x1,29); tfr(x0,x1,16); tfr(x0,x1,24);
  x0 += ks1; x1 += ks2 + 4u;
  tfr(x0,x1,13); tfr(x0,x1,15); tfr(x0,x1,26); tfr(x0,x1,6);
  x0 += ks2; x1 += ks0 + 5u;
  unsigned bits = x0 ^ x1;
  unsigned fb = (bits >> 9) | 0x3f800000u;
  float f = __uint_as_float(fb) - 1.0f;        // [0,1)
  const float lo = -0.99999994f;               // nextafter(-1,0) in f32
  float val = f * 2.0f + lo;                   // maxval-minval == 2.0f exactly
  val = fmaxf(lo, val);
  return 1.4142135381698608f * xla_erfinv(val);  // f32(sqrt(2)) * erfinv
}

// ---------------- K1: vb = u @ [W_proj | B_w]^T + [bias|0], fp32 tiled ----------------
__global__ __launch_bounds__(256) void k1_gemm_vbx(const float* __restrict__ u,
    const float* __restrict__ Wp, const float* __restrict__ Wpb,
    const float* __restrict__ Bw, float* __restrict__ vb){
  __shared__ float As[64*36];
  __shared__ float Bs[32*145];
  const int tid = threadIdx.x;
  const int tm = tid >> 4, tn = tid & 15;
  const int m0 = blockIdx.x * 64;
  float acc[4][9];
  #pragma unroll
  for (int e=0;e<4;e++)
    #pragma unroll
    for (int jj=0;jj<9;jj++) acc[e][jj] = 0.f;

  for (int k0=0; k0<DMODEL; k0+=32){
    for (int idx = tid; idx < 512; idx += 256){
      int row = idx >> 3, kq = idx & 7;
      float4 t = *(const float4*)(u + (size_t)(m0+row)*DMODEL + k0 + kq*4);
      float* dst = As + row*36 + kq*4;
      dst[0]=t.x; dst[1]=t.y; dst[2]=t.z; dst[3]=t.w;
    }
    for (int idx = tid; idx < 1152; idx += 256){
      int n = idx >> 3, kq = idx & 7;
      float4 t = make_float4(0.f,0.f,0.f,0.f);
      if (n < 120)      t = *(const float4*)(Wp + (size_t)n*DMODEL + k0 + kq*4);
      else if (n < 136) t = *(const float4*)(Bw + (size_t)(n-120)*DMODEL + k0 + kq*4);
      Bs[(kq*4+0)*145 + n] = t.x;
      Bs[(kq*4+1)*145 + n] = t.y;
      Bs[(kq*4+2)*145 + n] = t.z;
      Bs[(kq*4+3)*145 + n] = t.w;
    }
    __syncthreads();
    #pragma unroll
    for (int k=0;k<32;k++){
      float a[4], bb[9];
      #pragma unroll
      for (int e=0;e<4;e++) a[e] = As[(4*tm+e)*36 + k];
      #pragma unroll
      for (int jj=0;jj<9;jj++) bb[jj] = Bs[k*145 + tn + 16*jj];
      #pragma unroll
      for (int e=0;e<4;e++)
        #pragma unroll
        for (int jj=0;jj<9;jj++)
          acc[e][jj] = fmaf(a[e], bb[jj], acc[e][jj]);
    }
    __syncthreads();
  }
  #pragma unroll
  for (int e=0;e<4;e++){
    int row = m0 + 4*tm + e;
    #pragma unroll
    for (int jj=0;jj<9;jj++){
      int n = tn + 16*jj;
      if (n < 136){
        float o = acc[e][jj];
        if (n < 120) o += Wpb[n];
        vb[(size_t)row*VB_STRIDE + n] = o;
      }
    }
  }
}

// ---------------- K2: per (b,t): A -> power-iter sigma -> scale -> W ; ortho accum ----------------
__global__ __launch_bounds__(256) void k2_build_w(const float* __restrict__ vb,
    float* __restrict__ Wg, float* __restrict__ ortho){
  __shared__ float Abuf[16][272];
  __shared__ float Sbuf[16][272];
  __shared__ float gred[16];
  const int g = threadIdx.x >> 4, r = threadIdx.x & 15;
  const int m = blockIdx.x * 16 + g;
  float* A = Abuf[g];
  float* S = Sbuf[g];
  const float* vrow = vb + (size_t)m * VB_STRIDE;

  #pragma unroll
  for (int c=0;c<16;c++){
    float val = 0.f;
    if (c > r)      val =  vrow[r*15 - (r*(r-1))/2 + (c-r-1)];
    else if (c < r) val = -vrow[c*15 - (c*(c-1))/2 + (r-c-1)];
    A[r*17+c] = val;
  }
  float uv = jax_randn((unsigned)m*16u + (unsigned)r);
  float nn = uv*uv;
  #pragma unroll
  for (int s=1;s<16;s<<=1) nn += __shfl_xor(nn, s, 16);
  uv = uv / fmaxf(sqrtf(nn), 1e-12f);
  __syncthreads();

  float vvec = 0.f, av = 0.f;
  #pragma unroll
  for (int it=0; it<2; ++it){
    float accv = 0.f;                       // (A^T u)[r]
    #pragma unroll
    for (int k=0;k<16;k++) accv += A[k*17+r] * __shfl(uv, k, 16);
    nn = accv*accv;
    #pragma unroll
    for (int s=1;s<16;s<<=1) nn += __shfl_xor(nn, s, 16);
    vvec = accv / fmaxf(sqrtf(nn), 1e-12f);
    accv = 0.f;                             // (A v)[r]
    #pragma unroll
    for (int k=0;k<16;k++) accv += A[r*17+k] * __shfl(vvec, k, 16);
    av = accv;
    nn = accv*accv;
    #pragma unroll
    for (int s=1;s<16;s<<=1) nn += __shfl_xor(nn, s, 16);
    uv = accv / fmaxf(sqrtf(nn), 1e-12f);
  }
  float sig = uv * av;
  #pragma unroll
  for (int s=1;s<16;s<<=1) sig += __shfl_xor(sig, s, 16);
  sig = fabsf(sig);
  const float scale = 0.3f / fmaxf(sig, 0.3f);
  __syncthreads();
  #pragma unroll
  for (int c=0;c<16;c++) A[r*17+c] *= scale;
  __syncthreads();

  float arow[16];
  #pragma unroll
  for (int k=0;k<16;k++) arow[k] = A[r*17+k];
  #pragma unroll
  for (int j=0;j<16;j++){                   // S = A@A
    float accv = 0.f;
    #pragma unroll
    for (int k=0;k<16;k++) accv += arow[k] * A[k*17+j];
    S[r*17+j] = accv;
  }
  __syncthreads();
  float srow[16];
  #pragma unroll
  for (int k=0;k<16;k++) srow[k] = S[r*17+k];
  float wrow[16];
  #pragma unroll
  for (int j=0;j<16;j++){                   // W = I - 2A + 2S - 2AS + SS
    float as_=0.f, ss=0.f;
    #pragma unroll
    for (int k=0;k<16;k++){ float skj = S[k*17+j]; as_ += arow[k]*skj; ss += srow[k]*skj; }
    float wv = -2.f*arow[j] + 2.f*srow[j] - 2.f*as_ + ss;
    if (j==r) wv += 1.f;
    wrow[j] = wv;
  }
  float4* wout = (float4*)(Wg + (size_t)m*256 + r*16);
  wout[0] = make_float4(wrow[0],wrow[1],wrow[2],wrow[3]);
  wout[1] = make_float4(wrow[4],wrow[5],wrow[6],wrow[7]);
  wout[2] = make_float4(wrow[8],wrow[9],wrow[10],wrow[11]);
  wout[3] = make_float4(wrow[12],wrow[13],wrow[14],wrow[15]);

  __syncthreads();
  #pragma unroll
  for (int j=0;j<16;j++) A[r*17+j] = wrow[j];
  __syncthreads();
  float dev = 0.f;
  #pragma unroll
  for (int j=0;j<16;j++){
    float accv = 0.f;
    #pragma unroll
    for (int k=0;k<16;k++) accv += A[k*17+r]*A[k*17+j];
    if (j==r) accv -= 1.f;
    dev += accv*accv;
  }
  #pragma unroll
  for (int s=1;s<16;s<<=1) dev += __shfl_xor(dev, s, 16);
  if (r==0) gred[g] = sqrtf(dev);
  __syncthreads();
  if (threadIdx.x==0){
    float t=0.f;
    #pragma unroll
    for (int i=0;i<16;i++) t += gred[i];
    atomicAdd(ortho, t);
  }
}

// ---------------- K3a: per-chunk reduce in fp64: M_c = prod W, s_c (h0=0) ----------------
__global__ __launch_bounds__(64) void k3a_chunk_reduce(const float* __restrict__ Wg,
    const float* __restrict__ vb, double* __restrict__ Msum){
  const int chunk = blockIdx.x;
  const int b = chunk >> 6, c = chunk & 63;
  const int lane = threadIdx.x, r = lane & 15, g = lane >> 4;
  __shared__ double Mb[2][16*20];
  __shared__ double sb[16];
  #pragma unroll
  for (int cc=0;cc<4;cc++) Mb[0][r*20 + 4*g + cc] = (r == 4*g+cc) ? 1.0 : 0.0;
  if (lane < 16) sb[lane] = 0.0;
  __syncthreads();
  const size_t mbase = (size_t)b*SEQN + (size_t)c*CLEN;
  float4 wq = *(const float4*)(Wg + mbase*256 + r*16 + 4*g);
  float bx = vb[mbase*VB_STRIDE + 120 + r];
  int p = 0;
  for (int t=0;t<CLEN;++t){
    float4 wn = make_float4(0.f,0.f,0.f,0.f); float bxn = 0.f;
    if (t+1 < CLEN){
      wn  = *(const float4*)(Wg + (mbase+t+1)*256 + r*16 + 4*g);
      bxn = vb[(mbase+t+1)*VB_STRIDE + 120 + r];
    }
    const double* M = Mb[p];
    double a0=0.0,a1=0.0,a2=0.0,a3=0.0, sacc=0.0;
    #pragma unroll
    for (int kg=0;kg<4;kg++){
      float wk0 = __shfl(wq.x, r + 16*kg);
      float wk1 = __shfl(wq.y, r + 16*kg);
      float wk2 = __shfl(wq.z, r + 16*kg);
      float wk3 = __shfl(wq.w, r + 16*kg);
      float wkv[4] = {wk0,wk1,wk2,wk3};
      #pragma unroll
      for (int e=0;e<4;e++){
        int k = 4*kg + e;
        double w = (double)wkv[e];
        const double* mrow = M + k*20 + 4*g;
        a0 = fma(w, mrow[0], a0);
        a1 = fma(w, mrow[1], a1);
        a2 = fma(w, mrow[2], a2);
        a3 = fma(w, mrow[3], a3);
        sacc = fma(w, sb[k], sacc);
      }
    }
    __syncthreads();
    double* Mn = Mb[1-p];
    Mn[r*20+4*g+0]=a0; Mn[r*20+4*g+1]=a1; Mn[r*20+4*g+2]=a2; Mn[r*20+4*g+3]=a3;
    if (g==0) sb[r] = sacc + (double)bx;
    __syncthreads();
    p ^= 1;
    wq = wn; bx = bxn;
  }
  double* out = Msum + (size_t)chunk*272;
  #pragma unroll
  for (int cc=0;cc<4;cc++) out[r*16+4*g+cc] = Mb[p][r*20+4*g+cc];
  if (lane<16) out[256+lane] = sb[lane];
}

// ---------------- K3b: exclusive affine prefix over chunk summaries, fp64 ----------------
__global__ __launch_bounds__(64) void k3b_prefix(const double* __restrict__ Msum,
    double* __restrict__ hstart){
  const int b = blockIdx.x;
  const int lane = threadIdx.x, r = lane & 15, g = lane >> 4;
  __shared__ double q[16];
  if (lane < 16) q[lane] = 0.0;
  __syncthreads();
  const double* base = Msum + (size_t)b*CHUNKS*272;
  for (int c=0;c<CHUNKS;++c){
    const double* bc = base + (size_t)c*272;
    if (lane < 16) hstart[((size_t)b*CHUNKS + c)*16 + lane] = q[lane];
    double part = bc[r*16+4*g+0]*q[4*g+0] + bc[r*16+4*g+1]*q[4*g+1]
                + bc[r*16+4*g+2]*q[4*g+2] + bc[r*16+4*g+3]*q[4*g+3];
    part += __shfl_xor(part, 16);
    part += __shfl_xor(part, 32);
    __syncthreads();
    if (g==0) q[r] = part + bc[256+r];
    __syncthreads();
  }
}

// ---------------- K3c: re-apply within chunk from h_start (fp64 state), write h (f32) ----------------
__global__ __launch_bounds__(64) void k3c_apply(const float* __restrict__ Wg,
    const float* __restrict__ vb, const double* __restrict__ hstart,
    float* __restrict__ hout){
  const int chunk = blockIdx.x;
  const int b = chunk >> 6, c = chunk & 63;
  const int lane = threadIdx.x, r = lane & 15, g = lane >> 4;
  __shared__ double h[16];
  if (lane < 16) h[lane] = hstart[(size_t)chunk*16 + lane];
  __syncthreads();
  const size_t mbase = (size_t)b*SEQN + (size_t)c*CLEN;
  float4 wq = *(const float4*)(Wg + mbase*256 + r*16 + 4*g);
  float bx = vb[mbase*VB_STRIDE + 120 + r];
  for (int t=0;t<CLEN;++t){
    float4 wn = make_float4(0.f,0.f,0.f,0.f); float bxn = 0.f;
    if (t+1 < CLEN){
      wn  = *(const float4*)(Wg + (mbase+t+1)*256 + r*16 + 4*g);
      bxn = vb[(mbase+t+1)*VB_STRIDE + 120 + r];
    }
    double part = (double)wq.x*h[4*g+0] + (double)wq.y*h[4*g+1]
                + (double)wq.z*h[4*g+2] + (double)wq.w*h[4*g+3];
    part += __shfl_xor(part, 16);
    part += __shfl_xor(part, 32);
    __syncthreads();
    if (g==0){
      double nh = part + (double)bx;
      h[r] = nh;
      hout[(mbase+t)*16 + r] = (float)nh;
    }
    __syncthreads();
    wq = wn; bx = bxn;
  }
}

// ---------------- K4: y = h @ C^T + u*D ; append ortho_dev ----------------
__device__ __forceinline__ float dot4f(float4 a, float4 b){
  return a.x*b.x + a.y*b.y + a.z*b.z + a.w*b.w;
}

__global__ __launch_bounds__(256) void k4_out(const float* __restrict__ hbuf,
    const float* __restrict__ u, const float* __restrict__ Cw,
    const float* __restrict__ D, const float* __restrict__ ortho,
    float* __restrict__ y, int write_ortho){
  __shared__ float hl[256];
  const int m0 = blockIdx.x * 16;
  hl[threadIdx.x] = hbuf[(size_t)m0*16 + threadIdx.x];
  __syncthreads();
  const int col = threadIdx.x * 4;
  float4 cm[4][4];
  #pragma unroll
  for (int cc=0;cc<4;cc++)
    #pragma unroll
    for (int jj=0;jj<4;jj++)
      cm[cc][jj] = *(const float4*)(Cw + (size_t)(col+cc)*16 + jj*4);
  float4 d4 = *(const float4*)(D + col);
  #pragma unroll
  for (int row=0;row<16;row++){
    const float4* hr = (const float4*)(hl + row*16);
    float4 h0=hr[0], h1=hr[1], h2=hr[2], h3=hr[3];
    float4 o;
    o.x = dot4f(cm[0][0],h0)+dot4f(cm[0][1],h1)+dot4f(cm[0][2],h2)+dot4f(cm[0][3],h3);
    o.y = dot4f(cm[1][0],h0)+dot4f(cm[1][1],h1)+dot4f(cm[1][2],h2)+dot4f(cm[1][3],h3);
    o.z = dot4f(cm[2][0],h0)+dot4f(cm[2][1],h1)+dot4f(cm[2][2],h2)+dot4f(cm[2][3],h3);
    o.w = dot4f(cm[3][0],h0)+dot4f(cm[3][1],h1)+dot4f(cm[3][2],h2)+dot4f(cm[3][3],h3);
    size_t off = (size_t)(m0+row)*DMODEL + col;
    float4 u4 = *(const float4*)(u + off);
    o.x += u4.x*d4.x; o.y += u4.y*d4.y; o.z += u4.z*d4.z; o.w += u4.w*d4.w;
    *(float4*)(y + off) = o;
  }
  if (write_ortho && blockIdx.x==0 && threadIdx.x==0)
    y[YSIZE] = ortho[0] * (1.0f/32768.0f);
}

// ---------------- launcher ----------------
extern "C" void kernel_launch(void* const* d_in, const int* in_sizes, int n_in,
                              void* d_out, int out_size, void* d_ws, size_t ws_size,
                              hipStream_t stream){
  const float* u   = (const float*)d_in[0];
  const float* Wp  = (const float*)d_in[1];
  const float* Wpb = (const float*)d_in[2];
  const float* Bw  = (const float*)d_in[3];
  const float* Cw  = (const float*)d_in[4];
  const float* D   = (const float*)d_in[5];
  float* y = (float*)d_out;

  float* f      = (float*)d_ws;
  float* vb     = f;                                    // 32768*136 f
  float* Wg     = vb  + (size_t)MTOT*VB_STRIDE;         // 32768*256 f
  float* hbuf   = Wg  + (size_t)MTOT*256;               // 32768*16 f
  double* Msum  = (double*)(hbuf + (size_t)MTOT*16);    // 512*272 d (8B aligned: even float count)
  double* hstart= Msum + (size_t)BATCHN*CHUNKS*272;     // 512*16 d
  float* ortho  = (float*)(hstart + (size_t)BATCHN*CHUNKS*16); // 1 f

  int write_ortho = (out_size > (int)1 && (size_t)out_size > YSIZE) ? 1 : 0;

  hipMemsetAsync(ortho, 0, sizeof(float), stream);
  hipLaunchKernelGGL(k1_gemm_vbx,     dim3(MTOT/64), dim3(256), 0, stream, u, Wp, Wpb, Bw, vb);
  hipLaunchKernelGGL(k2_build_w,      dim3(MTOT/16), dim3(256), 0, stream, vb, Wg, ortho);
  hipLaunchKernelGGL(k3a_chunk_reduce,dim3(BATCHN*CHUNKS), dim3(64), 0, stream, Wg, vb, Msum);
  hipLaunchKernelGGL(k3b_prefix,      dim3(BATCHN), dim3(64), 0, stream, Msum, hstart);
  hipLaunchKernelGGL(k3c_apply,       dim3(BATCHN*CHUNKS), dim3(64), 0, stream, Wg, vb, hstart, hbuf);
  hipLaunchKernelGGL(k4_out,          dim3(MTOT/16), dim3(256), 0, stream, hbuf, u, Cw, D, ortho, y, write_ortho);
}

// Round 3
// 501.335 us; speedup vs baseline: 1.2998x; 1.2998x over previous
//
#include <hip/hip_runtime.h>
#include <hip/hip_bf16.h>
#include <math.h>

#define BATCHN 8
#define SEQN 4096
#define DMODEL 1024
#define MTOT (BATCHN*SEQN)      // 32768
#define VB_STRIDE 136           // 120 skew params | 16 Bx
#define CHUNKS 64
#define CLEN 64
#define YSIZE ((size_t)MTOT*DMODEL)
#define BN_ROWS 144             // 136 padded to 9*16

typedef __attribute__((ext_vector_type(8))) short short8;
typedef __attribute__((ext_vector_type(4))) float f32x4;

__device__ __forceinline__ unsigned short f2bf(float x){
  __hip_bfloat16 h = __float2bfloat16(x);
  return *(unsigned short*)&h;
}
__device__ __forceinline__ float bf2f(unsigned short b){
  __hip_bfloat16 h; *(unsigned short*)&h = b;
  return __bfloat162float(h);
}

// ---------------- threefry2x32 (partitionable) + XLA erfinv ----------------
__device__ __forceinline__ unsigned rotl32(unsigned x, int d){ return (x<<d)|(x>>(32-d)); }
__device__ __forceinline__ void tfr(unsigned &x0, unsigned &x1, int r){ x0 += x1; x1 = rotl32(x1,r); x1 ^= x0; }

__device__ __forceinline__ float xla_erfinv(float x){
  float w = -log1pf(-x*x);
  float p;
  if (w < 5.0f){
    w = w - 2.5f;
    p = 2.81022636e-08f;
    p = fmaf(p, w, 3.43273939e-07f);
    p = fmaf(p, w, -3.5233877e-06f);
    p = fmaf(p, w, -4.39150654e-06f);
    p = fmaf(p, w, 0.00021858087f);
    p = fmaf(p, w, -0.00125372503f);
    p = fmaf(p, w, -0.00417768164f);
    p = fmaf(p, w, 0.246640727f);
    p = fmaf(p, w, 1.50140941f);
  } else {
    w = sqrtf(w) - 3.0f;
    p = -0.000200214257f;
    p = fmaf(p, w, 0.000100950558f);
    p = fmaf(p, w, 0.00134934322f);
    p = fmaf(p, w, -0.00367342844f);
    p = fmaf(p, w, 0.00573950773f);
    p = fmaf(p, w, -0.0076224613f);
    p = fmaf(p, w, 0.00943887047f);
    p = fmaf(p, w, 1.00167406f);
    p = fmaf(p, w, 2.83297682f);
  }
  return p * x;
}

__device__ float jax_randn(unsigned I){
  unsigned x0 = 0u, x1 = I;
  const unsigned ks2 = 0x1BD11BDBu;
  x0 += 0u; x1 += 1u;
  tfr(x0,x1,13); tfr(x0,x1,15); tfr(x0,x1,26); tfr(x0,x1,6);
  x0 += 1u; x1 += ks2 + 1u;
  tfr(x0,x1,17); tfr(x0,x1,29); tfr(x0,x1,16); tfr(x0,x1,24);
  x0 += ks2; x1 += 0u + 2u;
  tfr(x0,x1,13); tfr(x0,x1,15); tfr(x0,x1,26); tfr(x0,x1,6);
  x0 += 0u; x1 += 1u + 3u;
  tfr(x0,x1,17); tfr(x0,x1,29); tfr(x0,x1,16); tfr(x0,x1,24);
  x0 += 1u; x1 += ks2 + 4u;
  tfr(x0,x1,13); tfr(x0,x1,15); tfr(x0,x1,26); tfr(x0,x1,6);
  x0 += ks2; x1 += 0u + 5u;
  unsigned bits = x0 ^ x1;
  unsigned fb = (bits >> 9) | 0x3f800000u;
  float f = __uint_as_float(fb) - 1.0f;
  const float lo = -0.99999994f;
  float val = f * 2.0f + lo;
  val = fmaxf(lo, val);
  return 1.4142135381698608f * xla_erfinv(val);
}

// ---------------- K0: pre-split [Wp|Bw|0] (144x1024) into bf16 hi/lo ----------------
__global__ __launch_bounds__(256) void k0_presplit(const float* __restrict__ Wp,
    const float* __restrict__ Bw, unsigned short* __restrict__ Bhi,
    unsigned short* __restrict__ Blo){
  int i = blockIdx.x*256 + threadIdx.x;      // one thread per 4 elements
  if (i >= BN_ROWS*DMODEL/4) return;
  int n = i >> 8;                            // 1024/4 = 256 quads per row
  int k = (i & 255) * 4;
  float4 t = make_float4(0.f,0.f,0.f,0.f);
  if (n < 120)      t = *(const float4*)(Wp + (size_t)n*DMODEL + k);
  else if (n < 136) t = *(const float4*)(Bw + (size_t)(n-120)*DMODEL + k);
  unsigned short h[4], l[4];
  float v[4] = {t.x,t.y,t.z,t.w};
  #pragma unroll
  for (int j=0;j<4;j++){
    h[j] = f2bf(v[j]);
    l[j] = f2bf(v[j] - bf2f(h[j]));
  }
  size_t off = (size_t)n*DMODEL + k;
  *(ushort4*)(Bhi + off) = make_ushort4(h[0],h[1],h[2],h[3]);
  *(ushort4*)(Blo + off) = make_ushort4(l[0],l[1],l[2],l[3]);
}

// ---------------- K1: vb = u @ [Wp|Bw]^T + bias via split-bf16 MFMA ----------------
// block: 128 threads = 2 waves; BM=64 (wave w owns rows w*32..w*32+31); N=144; K-chunk 32
__global__ __launch_bounds__(128) void k1_mfma(const float* __restrict__ u,
    const unsigned short* __restrict__ Bhi, const unsigned short* __restrict__ Blo,
    const float* __restrict__ Wpb, float* __restrict__ vb){
  __shared__ unsigned short As_hi[64*40];
  __shared__ unsigned short As_lo[64*40];
  __shared__ unsigned short Bs_hi[BN_ROWS*40];
  __shared__ unsigned short Bs_lo[BN_ROWS*40];

  const int tid  = threadIdx.x;
  const int wave = tid >> 6;
  const int lane = tid & 63;
  const int quad = lane >> 4;
  const int lrow = lane & 15;
  const int m0   = blockIdx.x * 64;

  // bias per n-tile
  float biasv[9];
  #pragma unroll
  for (int t=0;t<9;t++){
    int col = t*16 + lrow;
    biasv[t] = (col < 120) ? Wpb[col] : 0.f;
  }

  f32x4 acc[2][9];
  #pragma unroll
  for (int s=0;s<2;s++)
    #pragma unroll
    for (int t=0;t<9;t++)
      acc[s][t] = (f32x4){0.f,0.f,0.f,0.f};

  const int arow = tid & 63;          // A staging: row, 16 k per thread
  const int ak0  = (tid >> 6) * 16;

  for (int c=0;c<DMODEL/32;c++){
    // ---- stage A (fp32 -> bf16 hi/lo) ----
    {
      const float* src = u + (size_t)(m0+arow)*DMODEL + c*32 + ak0;
      float va[16];
      #pragma unroll
      for (int q=0;q<4;q++){
        float4 t4 = *(const float4*)(src + q*4);
        va[q*4+0]=t4.x; va[q*4+1]=t4.y; va[q*4+2]=t4.z; va[q*4+3]=t4.w;
      }
      unsigned short hh[16], ll[16];
      #pragma unroll
      for (int j=0;j<16;j++){
        hh[j] = f2bf(va[j]);
        ll[j] = f2bf(va[j] - bf2f(hh[j]));
      }
      unsigned short* dh = As_hi + arow*40 + ak0;
      unsigned short* dl = As_lo + arow*40 + ak0;
      #pragma unroll
      for (int half=0; half<2; half++){
        short8 ph, pl;
        #pragma unroll
        for (int j=0;j<8;j++){ ph[j] = (short)hh[half*8+j]; pl[j] = (short)ll[half*8+j]; }
        *(short8*)(dh + half*8) = ph;
        *(short8*)(dl + half*8) = pl;
      }
    }
    // ---- stage B (pre-split bf16, 144x32 tile) ----
    for (int i = tid; i < BN_ROWS*4; i += 128){   // 16B units: 4 per row
      int n  = i >> 2;
      int kq = (i & 3) * 8;
      size_t goff = (size_t)n*DMODEL + c*32 + kq;
      *(short8*)(Bs_hi + n*40 + kq) = *(const short8*)(Bhi + goff);
      *(short8*)(Bs_lo + n*40 + kq) = *(const short8*)(Blo + goff);
    }
    __syncthreads();

    // ---- compute ----
    short8 ahi[2], alo[2];
    #pragma unroll
    for (int s=0;s<2;s++){
      int row = wave*32 + s*16 + lrow;
      ahi[s] = *(const short8*)(As_hi + row*40 + quad*8);
      alo[s] = *(const short8*)(As_lo + row*40 + quad*8);
    }
    #pragma unroll
    for (int t=0;t<9;t++){
      short8 bhi = *(const short8*)(Bs_hi + (t*16+lrow)*40 + quad*8);
      short8 blo = *(const short8*)(Bs_lo + (t*16+lrow)*40 + quad*8);
      #pragma unroll
      for (int s=0;s<2;s++){
        acc[s][t] = __builtin_amdgcn_mfma_f32_16x16x32_bf16(ahi[s], bhi, acc[s][t], 0,0,0);
        acc[s][t] = __builtin_amdgcn_mfma_f32_16x16x32_bf16(ahi[s], blo, acc[s][t], 0,0,0);
        acc[s][t] = __builtin_amdgcn_mfma_f32_16x16x32_bf16(alo[s], bhi, acc[s][t], 0,0,0);
      }
    }
    __syncthreads();
  }

  // ---- store: lane L reg i -> row quad*4+i, col lrow ----
  #pragma unroll
  for (int s=0;s<2;s++){
    #pragma unroll
    for (int t=0;t<9;t++){
      int col = t*16 + lrow;
      if (col < VB_STRIDE){
        #pragma unroll
        for (int i=0;i<4;i++){
          int row = m0 + wave*32 + s*16 + quad*4 + i;
          vb[(size_t)row*VB_STRIDE + col] = acc[s][t][i] + biasv[t];
        }
      }
    }
  }
}

// ---------------- K2: A -> power-iter sigma -> scale -> W ; ortho accum ----------------
// 128 threads = 8 groups of 16; one matrix per group
__global__ __launch_bounds__(128) void k2_build_w(const float* __restrict__ vb,
    float* __restrict__ Wg, float* __restrict__ ortho){
  __shared__ float Af[8*324];
  __shared__ float Sf[8*324];
  __shared__ float gsum[8];
  const int tid = threadIdx.x;
  const int grp = tid >> 4;
  const int r   = tid & 15;
  const int m   = blockIdx.x*8 + grp;
  float* A = Af + grp*324;
  float* S = Sf + grp*324;
  const float* vrow = vb + (size_t)m*VB_STRIDE;

  // skew row r in registers
  float a_s[16];
  #pragma unroll
  for (int c=0;c<16;c++){
    float val = 0.f;
    if (c > r)      val =  vrow[r*15 - (r*(r-1))/2 + (c-r-1)];
    else if (c < r) val = -vrow[c*15 - (c*(c-1))/2 + (r-c-1)];
    a_s[c] = val;
  }

  // power iteration (register-only): A^T = -A
  float uv = jax_randn((unsigned)m*16u + (unsigned)r);
  float nn = uv*uv;
  #pragma unroll
  for (int s=1;s<16;s<<=1) nn += __shfl_xor(nn, s, 16);
  uv = uv / fmaxf(sqrtf(nn), 1e-12f);

  float t2 = 0.f;
  #pragma unroll
  for (int it=0; it<2; ++it){
    float t1 = 0.f;
    #pragma unroll
    for (int k=0;k<16;k++) t1 += a_s[k]*__shfl(uv, k, 16);
    t1 = -t1;                                   // A^T u
    nn = t1*t1;
    #pragma unroll
    for (int s=1;s<16;s<<=1) nn += __shfl_xor(nn, s, 16);
    float vvec = t1 / fmaxf(sqrtf(nn), 1e-12f);
    t2 = 0.f;
    #pragma unroll
    for (int k=0;k<16;k++) t2 += a_s[k]*__shfl(vvec, k, 16);  // A v
    nn = t2*t2;
    #pragma unroll
    for (int s=1;s<16;s<<=1) nn += __shfl_xor(nn, s, 16);
    uv = t2 / fmaxf(sqrtf(nn), 1e-12f);
  }
  float sig = uv * t2;
  #pragma unroll
  for (int s=1;s<16;s<<=1) sig += __shfl_xor(sig, s, 16);
  sig = fabsf(sig);
  const float scale = 0.3f / fmaxf(sig, 0.3f);
  #pragma unroll
  for (int k=0;k<16;k++) a_s[k] *= scale;

  // write A rows to LDS
  #pragma unroll
  for (int q=0;q<4;q++)
    *(float4*)(A + r*20 + q*4) = make_float4(a_s[q*4],a_s[q*4+1],a_s[q*4+2],a_s[q*4+3]);
  __syncthreads();

  // S = A@A (row r): s = sum_k a[k]*Arow(k)
  float s_s[16];
  #pragma unroll
  for (int j=0;j<16;j++) s_s[j] = 0.f;
  #pragma unroll
  for (int k=0;k<16;k++){
    #pragma unroll
    for (int q=0;q<4;q++){
      float4 ak = *(const float4*)(A + k*20 + q*4);
      s_s[q*4+0] = fmaf(a_s[k], ak.x, s_s[q*4+0]);
      s_s[q*4+1] = fmaf(a_s[k], ak.y, s_s[q*4+1]);
      s_s[q*4+2] = fmaf(a_s[k], ak.z, s_s[q*4+2]);
      s_s[q*4+3] = fmaf(a_s[k], ak.w, s_s[q*4+3]);
    }
  }
  #pragma unroll
  for (int q=0;q<4;q++)
    *(float4*)(S + r*20 + q*4) = make_float4(s_s[q*4],s_s[q*4+1],s_s[q*4+2],s_s[q*4+3]);
  __syncthreads();

  // AS and SS rows
  float as_s[16], ss_s[16];
  #pragma unroll
  for (int j=0;j<16;j++){ as_s[j]=0.f; ss_s[j]=0.f; }
  #pragma unroll
  for (int k=0;k<16;k++){
    #pragma unroll
    for (int q=0;q<4;q++){
      float4 sk = *(const float4*)(S + k*20 + q*4);
      as_s[q*4+0] = fmaf(a_s[k], sk.x, as_s[q*4+0]);
      as_s[q*4+1] = fmaf(a_s[k], sk.y, as_s[q*4+1]);
      as_s[q*4+2] = fmaf(a_s[k], sk.z, as_s[q*4+2]);
      as_s[q*4+3] = fmaf(a_s[k], sk.w, as_s[q*4+3]);
      ss_s[q*4+0] = fmaf(s_s[k], sk.x, ss_s[q*4+0]);
      ss_s[q*4+1] = fmaf(s_s[k], sk.y, ss_s[q*4+1]);
      ss_s[q*4+2] = fmaf(s_s[k], sk.z, ss_s[q*4+2]);
      ss_s[q*4+3] = fmaf(s_s[k], sk.w, ss_s[q*4+3]);
    }
  }
  // W = I - 2A + 2S - 2AS + SS
  float w_s[16];
  #pragma unroll
  for (int j=0;j<16;j++){
    float wv = -2.f*a_s[j] + 2.f*s_s[j] - 2.f*as_s[j] + ss_s[j];
    if (j == r) wv += 1.f;
    w_s[j] = wv;
  }
  float4* wout = (float4*)(Wg + (size_t)m*256 + r*16);
  #pragma unroll
  for (int q=0;q<4;q++)
    wout[q] = make_float4(w_s[q*4],w_s[q*4+1],w_s[q*4+2],w_s[q*4+3]);

  // ortho dev: reuse A buffer for W
  __syncthreads();
  #pragma unroll
  for (int q=0;q<4;q++)
    *(float4*)(A + r*20 + q*4) = make_float4(w_s[q*4],w_s[q*4+1],w_s[q*4+2],w_s[q*4+3]);
  __syncthreads();
  float wt_s[16];
  #pragma unroll
  for (int j=0;j<16;j++) wt_s[j] = 0.f;
  #pragma unroll
  for (int k=0;k<16;k++){
    float ck = A[k*20 + r];                 // W[k][r]
    #pragma unroll
    for (int q=0;q<4;q++){
      float4 wk = *(const float4*)(A + k*20 + q*4);
      wt_s[q*4+0] = fmaf(ck, wk.x, wt_s[q*4+0]);
      wt_s[q*4+1] = fmaf(ck, wk.y, wt_s[q*4+1]);
      wt_s[q*4+2] = fmaf(ck, wk.z, wt_s[q*4+2]);
      wt_s[q*4+3] = fmaf(ck, wk.w, wt_s[q*4+3]);
    }
  }
  float dev = 0.f;
  #pragma unroll
  for (int j=0;j<16;j++){
    float v = wt_s[j] - ((j==r)?1.f:0.f);
    dev += v*v;
  }
  #pragma unroll
  for (int s=1;s<16;s<<=1) dev += __shfl_xor(dev, s, 16);
  if (r==0) gsum[grp] = sqrtf(dev);
  __syncthreads();
  if (tid==0){
    float t=0.f;
    #pragma unroll
    for (int i=0;i<8;i++) t += gsum[i];
    atomicAdd(ortho, t);
  }
}

// ---------------- K3a: per-chunk reduce in fp64 ----------------
__global__ __launch_bounds__(64) void k3a_chunk_reduce(const float* __restrict__ Wg,
    const float* __restrict__ vb, double* __restrict__ Msum){
  const int chunk = blockIdx.x;
  const int b = chunk >> 6, c = chunk & 63;
  const int lane = threadIdx.x, r = lane & 15, g = lane >> 4;
  __shared__ double Mb[2][16*20];
  __shared__ double sb[16];
  #pragma unroll
  for (int cc=0;cc<4;cc++) Mb[0][r*20 + 4*g + cc] = (r == 4*g+cc) ? 1.0 : 0.0;
  if (lane < 16) sb[lane] = 0.0;
  __syncthreads();
  const size_t mbase = (size_t)b*SEQN + (size_t)c*CLEN;
  float4 wq = *(const float4*)(Wg + mbase*256 + r*16 + 4*g);
  float bx = vb[mbase*VB_STRIDE + 120 + r];
  int p = 0;
  for (int t=0;t<CLEN;++t){
    float4 wn = make_float4(0.f,0.f,0.f,0.f); float bxn = 0.f;
    if (t+1 < CLEN){
      wn  = *(const float4*)(Wg + (mbase+t+1)*256 + r*16 + 4*g);
      bxn = vb[(mbase+t+1)*VB_STRIDE + 120 + r];
    }
    const double* M = Mb[p];
    double a0=0.0,a1=0.0,a2=0.0,a3=0.0, sacc=0.0;
    #pragma unroll
    for (int kg=0;kg<4;kg++){
      float wk0 = __shfl(wq.x, r + 16*kg);
      float wk1 = __shfl(wq.y, r + 16*kg);
      float wk2 = __shfl(wq.z, r + 16*kg);
      float wk3 = __shfl(wq.w, r + 16*kg);
      float wkv[4] = {wk0,wk1,wk2,wk3};
      #pragma unroll
      for (int e=0;e<4;e++){
        int k = 4*kg + e;
        double w = (double)wkv[e];
        const double* mrow = M + k*20 + 4*g;
        a0 = fma(w, mrow[0], a0);
        a1 = fma(w, mrow[1], a1);
        a2 = fma(w, mrow[2], a2);
        a3 = fma(w, mrow[3], a3);
        sacc = fma(w, sb[k], sacc);
      }
    }
    __syncthreads();
    double* Mn = Mb[1-p];
    Mn[r*20+4*g+0]=a0; Mn[r*20+4*g+1]=a1; Mn[r*20+4*g+2]=a2; Mn[r*20+4*g+3]=a3;
    if (g==0) sb[r] = sacc + (double)bx;
    __syncthreads();
    p ^= 1;
    wq = wn; bx = bxn;
  }
  double* out = Msum + (size_t)chunk*272;
  #pragma unroll
  for (int cc=0;cc<4;cc++) out[r*16+4*g+cc] = Mb[p][r*20+4*g+cc];
  if (lane<16) out[256+lane] = sb[lane];
}

// ---------------- K3b: exclusive affine prefix over chunk summaries, fp64, prefetched ----------------
__global__ __launch_bounds__(64) void k3b_prefix(const double* __restrict__ Msum,
    double* __restrict__ hstart){
  const int b = blockIdx.x;
  const int lane = threadIdx.x, r = lane & 15, g = lane >> 4;
  __shared__ double q[16];
  if (lane < 16) q[lane] = 0.0;
  __syncthreads();
  const double* base = Msum + (size_t)b*CHUNKS*272;
  double2 m01 = *(const double2*)(base + r*16 + 4*g);
  double2 m23 = *(const double2*)(base + r*16 + 4*g + 2);
  double sv = base[256 + r];
  for (int c=0;c<CHUNKS;++c){
    double2 n01, n23; double svn = 0.0;
    n01.x=n01.y=n23.x=n23.y=0.0;
    if (c+1 < CHUNKS){
      const double* bn = base + (size_t)(c+1)*272;
      n01 = *(const double2*)(bn + r*16 + 4*g);
      n23 = *(const double2*)(bn + r*16 + 4*g + 2);
      svn = bn[256 + r];
    }
    if (lane < 16) hstart[((size_t)b*CHUNKS + c)*16 + lane] = q[lane];
    double part = m01.x*q[4*g+0] + m01.y*q[4*g+1] + m23.x*q[4*g+2] + m23.y*q[4*g+3];
    part += __shfl_xor(part, 16);
    part += __shfl_xor(part, 32);
    __syncthreads();
    if (g==0) q[r] = part + sv;
    __syncthreads();
    m01 = n01; m23 = n23; sv = svn;
  }
}

// ---------------- K3c: re-apply within chunk, fp64 state ----------------
__global__ __launch_bounds__(64) void k3c_apply(const float* __restrict__ Wg,
    const float* __restrict__ vb, const double* __restrict__ hstart,
    float* __restrict__ hout){
  const int chunk = blockIdx.x;
  const int b = chunk >> 6, c = chunk & 63;
  const int lane = threadIdx.x, r = lane & 15, g = lane >> 4;
  __shared__ double h[16];
  if (lane < 16) h[lane] = hstart[(size_t)chunk*16 + lane];
  __syncthreads();
  const size_t mbase = (size_t)b*SEQN + (size_t)c*CLEN;
  float4 wq = *(const float4*)(Wg + mbase*256 + r*16 + 4*g);
  float bx = vb[mbase*VB_STRIDE + 120 + r];
  for (int t=0;t<CLEN;++t){
    float4 wn = make_float4(0.f,0.f,0.f,0.f); float bxn = 0.f;
    if (t+1 < CLEN){
      wn  = *(const float4*)(Wg + (mbase+t+1)*256 + r*16 + 4*g);
      bxn = vb[(mbase+t+1)*VB_STRIDE + 120 + r];
    }
    double part = (double)wq.x*h[4*g+0] + (double)wq.y*h[4*g+1]
                + (double)wq.z*h[4*g+2] + (double)wq.w*h[4*g+3];
    part += __shfl_xor(part, 16);
    part += __shfl_xor(part, 32);
    __syncthreads();
    if (g==0){
      double nh = part + (double)bx;
      h[r] = nh;
      hout[(mbase+t)*16 + r] = (float)nh;
    }
    __syncthreads();
    wq = wn; bx = bxn;
  }
}

// ---------------- K4: y = h @ C^T + u*D ; append ortho_dev ----------------
__device__ __forceinline__ float dot4f(float4 a, float4 b){
  return a.x*b.x + a.y*b.y + a.z*b.z + a.w*b.w;
}

__global__ __launch_bounds__(256) void k4_out(const float* __restrict__ hbuf,
    const float* __restrict__ u, const float* __restrict__ Cw,
    const float* __restrict__ D, const float* __restrict__ ortho,
    float* __restrict__ y, int write_ortho){
  __shared__ float hl[256];
  const int m0 = blockIdx.x * 16;
  hl[threadIdx.x] = hbuf[(size_t)m0*16 + threadIdx.x];
  __syncthreads();
  const int col = threadIdx.x * 4;
  float4 cm[4][4];
  #pragma unroll
  for (int cc=0;cc<4;cc++)
    #pragma unroll
    for (int jj=0;jj<4;jj++)
      cm[cc][jj] = *(const float4*)(Cw + (size_t)(col+cc)*16 + jj*4);
  float4 d4 = *(const float4*)(D + col);
  #pragma unroll
  for (int row=0;row<16;row++){
    const float4* hr = (const float4*)(hl + row*16);
    float4 h0=hr[0], h1=hr[1], h2=hr[2], h3=hr[3];
    float4 o;
    o.x = dot4f(cm[0][0],h0)+dot4f(cm[0][1],h1)+dot4f(cm[0][2],h2)+dot4f(cm[0][3],h3);
    o.y = dot4f(cm[1][0],h0)+dot4f(cm[1][1],h1)+dot4f(cm[1][2],h2)+dot4f(cm[1][3],h3);
    o.z = dot4f(cm[2][0],h0)+dot4f(cm[2][1],h1)+dot4f(cm[2][2],h2)+dot4f(cm[2][3],h3);
    o.w = dot4f(cm[3][0],h0)+dot4f(cm[3][1],h1)+dot4f(cm[3][2],h2)+dot4f(cm[3][3],h3);
    size_t off = (size_t)(m0+row)*DMODEL + col;
    float4 u4 = *(const float4*)(u + off);
    o.x += u4.x*d4.x; o.y += u4.y*d4.y; o.z += u4.z*d4.z; o.w += u4.w*d4.w;
    *(float4*)(y + off) = o;
  }
  if (write_ortho && blockIdx.x==0 && threadIdx.x==0)
    y[YSIZE] = ortho[0] * (1.0f/32768.0f);
}

// ---------------- launcher ----------------
extern "C" void kernel_launch(void* const* d_in, const int* in_sizes, int n_in,
                              void* d_out, int out_size, void* d_ws, size_t ws_size,
                              hipStream_t stream){
  const float* u   = (const float*)d_in[0];
  const float* Wp  = (const float*)d_in[1];
  const float* Wpb = (const float*)d_in[2];
  const float* Bw  = (const float*)d_in[3];
  const float* Cw  = (const float*)d_in[4];
  const float* D   = (const float*)d_in[5];
  float* y = (float*)d_out;

  float* f      = (float*)d_ws;
  float* vb     = f;                                    // 32768*136 f
  float* Wg     = vb  + (size_t)MTOT*VB_STRIDE;         // 32768*256 f
  float* hbuf   = Wg  + (size_t)MTOT*256;               // 32768*16 f
  double* Msum  = (double*)(hbuf + (size_t)MTOT*16);    // 512*272 d
  double* hstart= Msum + (size_t)BATCHN*CHUNKS*272;     // 512*16 d
  unsigned short* Bhi = (unsigned short*)(hstart + (size_t)BATCHN*CHUNKS*16); // 144*1024 us
  unsigned short* Blo = Bhi + (size_t)BN_ROWS*DMODEL;
  float* ortho  = (float*)(Blo + (size_t)BN_ROWS*DMODEL);

  int write_ortho = ((size_t)out_size > YSIZE) ? 1 : 0;

  hipMemsetAsync(ortho, 0, sizeof(float), stream);
  hipLaunchKernelGGL(k0_presplit,     dim3((BN_ROWS*DMODEL/4+255)/256), dim3(256), 0, stream, Wp, Bw, Bhi, Blo);
  hipLaunchKernelGGL(k1_mfma,         dim3(MTOT/64), dim3(128), 0, stream, u, Bhi, Blo, Wpb, vb);
  hipLaunchKernelGGL(k2_build_w,      dim3(MTOT/8), dim3(128), 0, stream, vb, Wg, ortho);
  hipLaunchKernelGGL(k3a_chunk_reduce,dim3(BATCHN*CHUNKS), dim3(64), 0, stream, Wg, vb, Msum);
  hipLaunchKernelGGL(k3b_prefix,      dim3(BATCHN), dim3(64), 0, stream, Msum, hstart);
  hipLaunchKernelGGL(k3c_apply,       dim3(BATCHN*CHUNKS), dim3(64), 0, stream, Wg, vb, hstart, hbuf);
  hipLaunchKernelGGL(k4_out,          dim3(MTOT/16), dim3(256), 0, stream, hbuf, u, Cw, D, ortho, y, write_ortho);
}